// Round 1
// 496.355 us; speedup vs baseline: 1.0417x; 1.0417x over previous
//
#include <hip/hip_runtime.h>
#include <stdint.h>

// Problem constants (MCB_42949672960828)
#define Bsz  1024
#define D0n  2048
#define D1n  2048
#define MMn  16000
#define N2   8000    // half-length complex FFT size
#define OUTn 3000
#define FBLK 512     // threads for FFT kernel

// Padded LDS layout: X index i -> i + i/20  (one float2 pad per 20)
// size 8400 float2 = 67.2 KB; 2 blocks/CU needs <=80KB/block -> OK.
#define XSZ  8400

typedef __attribute__((ext_vector_type(8))) short bf16x8;
typedef __attribute__((ext_vector_type(4))) float f32x4;

__device__ __forceinline__ unsigned short f2bf(float f) {
    union { float fv; uint32_t u; } v; v.fv = f;
    return (unsigned short)((v.u + 0x7fffu + ((v.u >> 16) & 1u)) >> 16);
}
__device__ __forceinline__ float2 bf2c(uint32_t v) {
    union { uint32_t u; float f; } a, b;
    a.u = v << 16; b.u = v & 0xffff0000u;
    return make_float2(a.f, b.f);
}
__device__ __forceinline__ uint32_t packbf(float2 v) {
    return (uint32_t)f2bf(v.x) | ((uint32_t)f2bf(v.y) << 16);
}

__device__ __forceinline__ float2 operator+(float2 a, float2 b){ return make_float2(a.x+b.x, a.y+b.y); }
__device__ __forceinline__ float2 operator-(float2 a, float2 b){ return make_float2(a.x-b.x, a.y-b.y); }
__device__ __forceinline__ float2 operator*(float s, float2 a){ return make_float2(s*a.x, s*a.y); }
__device__ __forceinline__ float2 cmul(float2 a, float2 b){ return make_float2(a.x*b.x - a.y*b.y, a.x*b.y + a.y*b.x); }

// async 16B global -> LDS (direct-to-shared DMA)
__device__ __forceinline__ void gll16(const void* g, void* l) {
    __builtin_amdgcn_global_load_lds(
        (const __attribute__((address_space(1))) uint32_t*)g,
        (__attribute__((address_space(3))) uint32_t*)l, 16, 0, 0);
}

// ---------------------------------------------------------------------------
// Twiddle table, N2 = 8000, radices [20,20,20].
// stage1 (NC=8000,M=400): tw[p*19+(u-1)] p<400       -> [0,7600)
// stage2 (NC=400, M=20):  tw[7600+p*19+(u-1)] p<20   -> [7600,7980)
// untangle: utw[k] = e^{-2pi i k/8000}, k<=4000      -> [7980,11981)
// ---------------------------------------------------------------------------
#define TWN 11981

__global__ __launch_bounds__(256) void tw_init_kernel(float2* __restrict__ tw) {
    int g = blockIdx.x * 256 + threadIdx.x;
    if (g >= TWN) return;
    float ang;
    if (g < 7600)      { int p = g / 19, u = g % 19 + 1;
                         ang = -6.28318530718f * (float)((p * u) % 8000) / 8000.f; }
    else if (g < 7980) { int e = g - 7600; int p = e / 19, u = e % 19 + 1;
                         ang = -6.28318530718f * (float)((p * u) % 400) / 400.f; }
    else               { int k = g - 7980;
                         ang = -6.28318530718f * (float)k / 8000.f; }
    float s, c; __sincosf(ang, &s, &c);
    tw[g] = make_float2(c, s);
}

// radix-R DFT butterfly; sgn = -1 forward, +1 inverse
template<int R>
__device__ __forceinline__ void dft_r(const float2* a, float2* A, float sgn) {
    if constexpr (R == 4) {
        float2 t0 = a[0] + a[2], t1 = a[0] - a[2];
        float2 t2 = a[1] + a[3], t3 = a[1] - a[3];
        float2 it3 = make_float2(-sgn * t3.y, sgn * t3.x);
        A[0] = t0 + t2;  A[2] = t0 - t2;
        A[1] = t1 + it3; A[3] = t1 - it3;
    } else if constexpr (R == 5) {
        const float c1 = 0.30901699f,  s1 = 0.95105652f;
        const float c2 = -0.80901699f, s2 = 0.58778525f;
        float2 t1 = a[1] + a[4], t3 = a[1] - a[4];
        float2 t2 = a[2] + a[3], t4 = a[2] - a[3];
        float2 b1 = a[0] + c1 * t1 + c2 * t2;
        float2 b2 = a[0] + c2 * t1 + c1 * t2;
        float2 u  = s1 * t3 + s2 * t4;
        float2 v  = s2 * t3 - s1 * t4;
        float2 iu = make_float2(-sgn * u.y, sgn * u.x);
        float2 iv = make_float2(-sgn * v.y, sgn * v.x);
        A[0] = a[0] + t1 + t2;
        A[1] = b1 + iu;  A[4] = b1 - iu;
        A[2] = b2 + iv;  A[3] = b2 - iv;
    } else {  // R == 20: n = n0 + 4*n1 (n0<4,n1<5), k = k1 + 5*k0 (k1<5,k0<4)
        float2 b[4][5];
#pragma unroll
        for (int n0 = 0; n0 < 4; n0++) {
            float2 t[5] = { a[n0], a[n0+4], a[n0+8], a[n0+12], a[n0+16] };
            dft_r<5>(t, b[n0], sgn);
        }
        const float E1c=0.95105652f,  E1s=0.30901699f;
        const float E2c=0.80901699f,  E2s=0.58778525f;
        const float E3c=0.58778525f,  E3s=0.80901699f;
        const float E4c=0.30901699f,  E4s=0.95105652f;
        const float E6c=-0.30901699f, E6s=0.95105652f;
        const float E8c=-0.80901699f, E8s=0.58778525f;
        const float E9c=-0.95105652f, E9s=0.30901699f;
        const float E12c=-0.80901699f,E12s=-0.58778525f;
        b[1][1] = cmul(b[1][1], make_float2(E1c,  sgn*E1s));
        b[1][2] = cmul(b[1][2], make_float2(E2c,  sgn*E2s));
        b[1][3] = cmul(b[1][3], make_float2(E3c,  sgn*E3s));
        b[1][4] = cmul(b[1][4], make_float2(E4c,  sgn*E4s));
        b[2][1] = cmul(b[2][1], make_float2(E2c,  sgn*E2s));
        b[2][2] = cmul(b[2][2], make_float2(E4c,  sgn*E4s));
        b[2][3] = cmul(b[2][3], make_float2(E6c,  sgn*E6s));
        b[2][4] = cmul(b[2][4], make_float2(E8c,  sgn*E8s));
        b[3][1] = cmul(b[3][1], make_float2(E3c,  sgn*E3s));
        b[3][2] = cmul(b[3][2], make_float2(E6c,  sgn*E6s));
        b[3][3] = cmul(b[3][3], make_float2(E9c,  sgn*E9s));
        b[3][4] = cmul(b[3][4], make_float2(E12c, sgn*E12s));
#pragma unroll
        for (int k1 = 0; k1 < 5; k1++) {
            float2 t[4] = { b[0][k1], b[1][k1], b[2][k1], b[3][k1] };
            float2 o[4];
            dft_r<4>(t, o, sgn);
            A[k1] = o[0]; A[k1+5] = o[1]; A[k1+10] = o[2]; A[k1+15] = o[3];
        }
    }
}

// In-place stage over padded X; twiddles from table (inverse = conj).
// Padded index math (pad = idx/20, exact because NC multiples of 20):
//   M=400: idx = p + 400t      -> xi = (p + p/20) + 420t
//   M=20:  idx = 400blk+p+20t  -> xi = 420blk + p + 21t
//   M=1:   idx = 20e + t       -> xi = 21e + t
template<int N, int NC, int R, bool INV>
__device__ __forceinline__ void fft_stage(float2* X, const float2* __restrict__ tw) {
    constexpr int M = NC / R;
    constexpr int NBF = N / R;
    constexpr float sgn = INV ? 1.0f : -1.0f;
    for (int e = threadIdx.x; e < NBF; e += FBLK) {
        const int blk = e / M;
        const int p   = e - blk * M;
        int xbase, xstride;
        if constexpr (M == 400)     { xbase = p + p / 20;      xstride = 420; }
        else if constexpr (M == 20) { xbase = blk * 420 + p;   xstride = 21; }
        else                        { xbase = 21 * e;          xstride = 1; }
        float2 a[R];
#pragma unroll
        for (int t = 0; t < R; t++) a[t] = X[xbase + xstride * t];
        if constexpr (INV && M > 1) {
#pragma unroll
            for (int u = 1; u < R; u++) {
                float2 w = tw[p * (R - 1) + (u - 1)];
                a[u] = cmul(a[u], make_float2(w.x, -w.y));
            }
        }
        float2 A[R];
        dft_r<R>(a, A, sgn);
        if constexpr (!INV && M > 1) {
#pragma unroll
            for (int u = 1; u < R; u++) {
                float2 w = tw[p * (R - 1) + (u - 1)];
                A[u] = cmul(A[u], w);
            }
        }
#pragma unroll
        for (int t = 0; t < R; t++) X[xbase + xstride * t] = A[t];
    }
}

// Fused forward last stage (M=1): DFT20, spill packed bf16 to global,
// zero own X slots in-place (next scatter needs zeroed X; slots are private
// to this butterfly so no barrier needed between read/zero).
__device__ __forceinline__ void fwd_s3_spill_zero(float2* X, uint32_t* __restrict__ c0row) {
    for (int e = threadIdx.x; e < 400; e += FBLK) {
        const int xb = 21 * e;
        float2 a[20];
#pragma unroll
        for (int t = 0; t < 20; t++) a[t] = X[xb + t];
        float2 A[20];
        dft_r<20>(a, A, -1.0f);
        const float2 z2 = make_float2(0.f, 0.f);
#pragma unroll
        for (int t = 0; t < 20; t++) X[xb + t] = z2;
        uint4* dst = (uint4*)(c0row + 20 * e);
#pragma unroll
        for (int q = 0; q < 5; q++)
            dst[q] = make_uint4(packbf(A[4*q]), packbf(A[4*q+1]),
                                packbf(A[4*q+2]), packbf(A[4*q+3]));
    }
}

// Fused inverse last stage (NC=8000, M=400): inverse twiddle + DFT20,
// write output rows straight to global (coalesced: lanes p consecutive),
// skipping the LDS writeback + separate output phase + final barrier.
__device__ __forceinline__ void inv_last_out(const float2* X, const float2* __restrict__ tw,
                                             uint32_t* __restrict__ zrow) {
    const float invN = 1.0f / (float)N2;
    for (int e = threadIdx.x; e < 400; e += FBLK) {
        const int p = e;
        const int xb = p + p / 20;
        float2 a[20];
#pragma unroll
        for (int t = 0; t < 20; t++) a[t] = X[xb + 420 * t];
#pragma unroll
        for (int u = 1; u < 20; u++) {
            float2 w = tw[p * 19 + (u - 1)];
            a[u] = cmul(a[u], make_float2(w.x, -w.y));
        }
        float2 A[20];
        dft_r<20>(a, A, 1.0f);
#pragma unroll
        for (int t = 0; t < 20; t++)
            zrow[p + 400 * t] = packbf(make_float2(A[t].x * invN, A[t].y * invN));
    }
}

// scrambled position of natural frequency k; radices (20,20,20), weights (400,20,1)
__device__ __forceinline__ int sigma_inv8k(int k) {
    return (k % 20) * 400 + ((k / 20) % 20) * 20 + (k / 400);
}

// padded float address for scatter into Xf (float index h in [0,16000))
__device__ __forceinline__ int fpad(int h) {
    int i = h >> 1;
    return 2 * (i + i / 20) + (h & 1);
}

// W conversion plumbing (fused into fft kernel; 6 batches of 4 float4/thread)
#define WU_TOT 12000000            // (OUTn*MMn)/4 float4 units
#define WU_STRIDE (Bsz * FBLK)     // 524288

__device__ __forceinline__ void w_issue(const float4* __restrict__ wsrc,
                                        float4* wr, int uid, int bi) {
#pragma unroll
    for (int j = 0; j < 4; j++) {
        size_t u = (size_t)uid + (size_t)(bi * 4 + j) * WU_STRIDE;
        if (u < WU_TOT) wr[j] = wsrc[u];
    }
}
__device__ __forceinline__ void w_consume(unsigned short* __restrict__ wbf,
                                          const float4* wr, int uid, int bi) {
#pragma unroll
    for (int j = 0; j < 4; j++) {
        size_t u = (size_t)uid + (size_t)(bi * 4 + j) * WU_STRIDE;
        if (u < WU_TOT) {
            uint2 pk;
            pk.x = (uint32_t)f2bf(wr[j].x) | ((uint32_t)f2bf(wr[j].y) << 16);
            pk.y = (uint32_t)f2bf(wr[j].z) | ((uint32_t)f2bf(wr[j].w) << 16);
            ((uint2*)wbf)[u] = pk;
        }
    }
}

// ---------------------------------------------------------------------------
// Kernel: count-sketch + circular convolution via even/odd packed half-length
// FFTs. Padded LDS (stride 21/20) kills the 16-way bank conflict on M=1
// stages; spill/output fused into the boundary stages (12 barriers vs 15).
// ---------------------------------------------------------------------------
__global__ __launch_bounds__(FBLK, 4) void fft_conv_kernel(
    const float* __restrict__ x0, const float* __restrict__ x1,
    const int* __restrict__ h0, const int* __restrict__ h1,
    const int* __restrict__ s0, const int* __restrict__ s1,
    const float2* __restrict__ tw,
    const float* __restrict__ W, unsigned short* __restrict__ wbf, int doW,
    uint32_t* __restrict__ c0g,       // [Bsz, 8000] bf16-pair spill
    unsigned short* __restrict__ zb)  // [Bsz, MMn] bf16
{
    __shared__ float2 X[XSZ];         // 67200 B (padded)
    const int b = blockIdx.x;
    const int tid = threadIdx.x;
    const int uid = b * FBLK + tid;
    const float4* wsrc = (const float4*)W;
    const float2* utw = tw + 7980;
    float* Xf = (float*)X;
    uint32_t* c0row = c0g + (size_t)b * N2;

    float4 wr[4];
    if (doW) w_issue(wsrc, wr, uid, 0);

    // ---- zero padded X ----
    for (int i = tid; i < XSZ; i += FBLK) X[i] = make_float2(0.f, 0.f);
    __syncthreads();

    // ---- scatter c0 (vectorized: exactly one float4/int4 per thread) ----
    {
        float4 xv = ((const float4*)(x0 + (size_t)b * D0n))[tid];
        int4   hv = ((const int4*)h0)[tid];
        int4   sv = ((const int4*)s0)[tid];
        atomicAdd(&Xf[fpad(hv.x)], xv.x * (float)(2 * sv.x - 1));
        atomicAdd(&Xf[fpad(hv.y)], xv.y * (float)(2 * sv.y - 1));
        atomicAdd(&Xf[fpad(hv.z)], xv.z * (float)(2 * sv.z - 1));
        atomicAdd(&Xf[fpad(hv.w)], xv.w * (float)(2 * sv.w - 1));
    }
    __syncthreads();

    // ---- FFT of c0 ----
    fft_stage<N2,8000,20,false>(X, tw);        __syncthreads();
    if (doW) { w_consume(wbf, wr, uid, 0); w_issue(wsrc, wr, uid, 1); }
    fft_stage<N2,400, 20,false>(X, tw + 7600); __syncthreads();
    if (doW) { w_consume(wbf, wr, uid, 1); w_issue(wsrc, wr, uid, 2); }
    fwd_s3_spill_zero(X, c0row);               // stage3 + spill + zero fused
    __syncthreads();
    if (doW) { w_consume(wbf, wr, uid, 2); w_issue(wsrc, wr, uid, 3); }

    // ---- scatter c1 ----
    {
        float4 xv = ((const float4*)(x1 + (size_t)b * D1n))[tid];
        int4   hv = ((const int4*)h1)[tid];
        int4   sv = ((const int4*)s1)[tid];
        atomicAdd(&Xf[fpad(hv.x)], xv.x * (float)(2 * sv.x - 1));
        atomicAdd(&Xf[fpad(hv.y)], xv.y * (float)(2 * sv.y - 1));
        atomicAdd(&Xf[fpad(hv.z)], xv.z * (float)(2 * sv.z - 1));
        atomicAdd(&Xf[fpad(hv.w)], xv.w * (float)(2 * sv.w - 1));
    }
    __syncthreads();

    // ---- FFT of c1 ----
    fft_stage<N2,8000,20,false>(X, tw);        __syncthreads();
    if (doW) { w_consume(wbf, wr, uid, 3); w_issue(wsrc, wr, uid, 4); }
    fft_stage<N2,400, 20,false>(X, tw + 7600); __syncthreads();
    if (doW) { w_consume(wbf, wr, uid, 4); w_issue(wsrc, wr, uid, 5); }
    fft_stage<N2,20,  20,false>(X, tw);        __syncthreads();
    // (barrier drained vmcnt -> C0 spill visible in L2 for read-back)

    // ---- untangle + multiply + retangle (pairs k, 8000-k) ----
    for (int t = tid; t <= 4000; t += FBLK) {
        int k;
        if (t == 4000) k = 4000;
        else { int d2 = t % 10, r = t / 10; k = (r / 20) + 20 * (r % 20) + 400 * d2; }
        int ka = k % 20, ka2 = (k / 20) % 20, kc = k / 400;
        int pa  = ka * 400 + ka2 * 20 + kc;
        int xpa = pa + ka * 20 + ka2;                 // pa + pa/20 (kc < 20)
        int kk = (k == 0) ? 0 : (N2 - k);
        int ma = kk % 20, ma2 = (kk / 20) % 20, mc = kk / 400;
        int pb  = ma * 400 + ma2 * 20 + mc;
        int xpb = pb + ma * 20 + ma2;                 // pb + pb/20 (mc < 20)
        float2 C1a = X[xpa], C1b = X[xpb];
        float2 C0a = bf2c(c0row[pa]), C0b = bf2c(c0row[pb]);
        float2 E0 = make_float2(0.5f * (C0a.x + C0b.x), 0.5f * (C0a.y - C0b.y));
        float2 dv0 = make_float2(C0a.x - C0b.x, C0a.y + C0b.y);
        float2 O0 = make_float2(0.5f * dv0.y, -0.5f * dv0.x);
        float2 E1 = make_float2(0.5f * (C1a.x + C1b.x), 0.5f * (C1a.y - C1b.y));
        float2 dv1 = make_float2(C1a.x - C1b.x, C1a.y + C1b.y);
        float2 O1 = make_float2(0.5f * dv1.y, -0.5f * dv1.x);
        float2 Wq = utw[k];
        float2 Ez = cmul(E0, E1) + cmul(Wq, cmul(O0, O1));
        float2 Oz = cmul(E0, O1) + cmul(O0, E1);
        X[xpa] = make_float2(Ez.x - Oz.y, Ez.y + Oz.x);       // D[k]
        X[xpb] = make_float2(Ez.x + Oz.y, Oz.x - Ez.y);       // D[8000-k]
    }
    __syncthreads();
    if (doW) w_consume(wbf, wr, uid, 5);

    // ---- inverse FFT ----
    fft_stage<N2,20,  20,true>(X, tw);        __syncthreads();
    fft_stage<N2,400, 20,true>(X, tw + 7600); __syncthreads();
    uint32_t* zrow = (uint32_t*)(zb + (size_t)b * MMn);
    inv_last_out(X, tw, zrow);                // last stage + scale + output fused
}

// ---------------------------------------------------------------------------
// Split-K GEMM: partial[s] = Z[:, ks:ke] @ Wb[:, ks:ke]^T  (validated R3/R4)
// ---------------------------------------------------------------------------
#define PCOLS 3072
#define PSTRIDE ((size_t)Bsz * PCOLS)

__global__ __launch_bounds__(256, 3) void gemm_sk_kernel(
    const unsigned short* __restrict__ Z,    // [1024,16000] bf16
    const unsigned short* __restrict__ Wb,   // [3000,16000] bf16
    float* __restrict__ part)                // [4][1024][3072] f32
{
    __shared__ __align__(16) unsigned char As[16384];
    __shared__ __align__(16) unsigned char Bs[16384];

    const int tid = threadIdx.x;
    const int n0 = blockIdx.x * 128;
    const int m0 = blockIdx.y * 128;
    const int sp = blockIdx.z;
    const int lane = tid & 63;
    const int w = tid >> 6, wm = w >> 1, wn = w & 1;
    const int lr = lane & 15, qh = lane >> 4;

    const unsigned char* aSrc[4]; const unsigned char* bSrc[4];
    int aLds[4], bLds[4];
#pragma unroll
    for (int i = 0; i < 4; i++) {
        int slot = i * 256 + tid;
        int r = slot >> 3, qp = slot & 7;
        int q = qp ^ (r & 7);
        aSrc[i] = (const unsigned char*)(Z + (size_t)(m0 + r) * MMn + q * 8);
        aLds[i] = slot * 16;
        int rw = n0 + r; if (rw > OUTn - 1) rw = OUTn - 1;
        bSrc[i] = (const unsigned char*)(Wb + (size_t)rw * MMn + q * 8);
        bLds[i] = slot * 16;
    }

    int aOff[4], bOff[4];
#pragma unroll
    for (int i = 0; i < 4; i++) {
        aOff[i] = (wm * 64 + i * 16 + lr) * 128 + ((qh ^ (lr & 7)) * 16);
        bOff[i] = (wn * 64 + i * 16 + lr) * 128 + ((qh ^ (lr & 7)) * 16);
    }

    f32x4 acc[4][4];
#pragma unroll
    for (int i = 0; i < 4; i++)
#pragma unroll
        for (int j = 0; j < 4; j++)
            acc[i][j] = (f32x4){0.f, 0.f, 0.f, 0.f};

    const int it_b = (250 * sp) / 4, it_e = (250 * (sp + 1)) / 4;
    for (int it = it_b; it < it_e; ++it) {
        const size_t koff = (size_t)it * 128;
        __syncthreads();
#pragma unroll
        for (int i = 0; i < 4; i++) {
            gll16(aSrc[i] + koff, As + aLds[i]);
            gll16(bSrc[i] + koff, Bs + bLds[i]);
        }
        __syncthreads();
#pragma unroll
        for (int kk = 0; kk < 2; kk++) {
            const int kx = kk << 6;
            bf16x8 af[4], bfv[4];
#pragma unroll
            for (int i = 0; i < 4; i++) af[i]  = *(const bf16x8*)(As + (aOff[i] ^ kx));
#pragma unroll
            for (int j = 0; j < 4; j++) bfv[j] = *(const bf16x8*)(Bs + (bOff[j] ^ kx));
#pragma unroll
            for (int i = 0; i < 4; i++)
#pragma unroll
                for (int j = 0; j < 4; j++)
                    acc[i][j] = __builtin_amdgcn_mfma_f32_16x16x32_bf16(
                        af[i], bfv[j], acc[i][j], 0, 0, 0);
        }
    }

    float* pdst = part + (size_t)sp * PSTRIDE;
#pragma unroll
    for (int j = 0; j < 4; j++) {
        int n = n0 + wn * 64 + j * 16 + lr;
#pragma unroll
        for (int i = 0; i < 4; i++) {
            int mb = m0 + wm * 64 + i * 16 + qh * 4;
#pragma unroll
            for (int reg = 0; reg < 4; reg++)
                pdst[(size_t)(mb + reg) * PCOLS + n] = acc[i][j][reg];
        }
    }
}

// out = relu(sum_s part[s] + bias)
__global__ __launch_bounds__(256) void reduce_kernel(
    const float* __restrict__ part, const float* __restrict__ bias,
    float* __restrict__ out)
{
    int idx = blockIdx.x * 256 + threadIdx.x;
    int b = idx / 750, oq = idx - b * 750;
    int o = oq * 4;
    const float* p = part + (size_t)b * PCOLS + o;
    float4 s0 = *(const float4*)(p);
    float4 s1 = *(const float4*)(p + PSTRIDE);
    float4 s2 = *(const float4*)(p + 2 * PSTRIDE);
    float4 s3 = *(const float4*)(p + 3 * PSTRIDE);
    float4 bv = *(const float4*)(bias + o);
    float4 r;
    r.x = s0.x + s1.x + s2.x + s3.x + bv.x; r.x = r.x > 0.f ? r.x : 0.f;
    r.y = s0.y + s1.y + s2.y + s3.y + bv.y; r.y = r.y > 0.f ? r.y : 0.f;
    r.z = s0.z + s1.z + s2.z + s3.z + bv.z; r.z = r.z > 0.f ? r.z : 0.f;
    r.w = s0.w + s1.w + s2.w + s3.w + bv.w; r.w = r.w > 0.f ? r.w : 0.f;
    *(float4*)(out + (size_t)b * OUTn + o) = r;
}

// ---------------------------------------------------------------------------
// Fallback GEMM (R2, validated): direct out, W f32 converted in-loop.
// ---------------------------------------------------------------------------
#define BM 64
#define BN 128
#define BK 32
#define LDK 40

__global__ __launch_bounds__(256) void gemm_kernel(
    const unsigned short* __restrict__ Z, const float* __restrict__ W,
    const float* __restrict__ bias, float* __restrict__ out)
{
    __shared__ __align__(16) unsigned short As2[BM * LDK];
    __shared__ __align__(16) unsigned short Bs2[BN * LDK];

    const int tid = threadIdx.x;
    const int m0 = blockIdx.y * BM;
    const int n0 = blockIdx.x * BN;
    const int lane = tid & 63;
    const int w  = tid >> 6;
    const int wm = w >> 1;
    const int wn = w & 1;

    const int ar = tid >> 2, aq = tid & 3;
    const uint4* aSrc = (const uint4*)(Z + (size_t)(m0 + ar) * MMn + aq * 8);
    unsigned short* aDst = As2 + ar * LDK + aq * 8;

    const float4* bSrc[4];
    unsigned short* bDst[4];
#pragma unroll
    for (int p = 0; p < 4; p++) {
        int ch = tid + 256 * p;
        int r = ch >> 3, q = ch & 7;
        int rw = n0 + r; if (rw > OUTn - 1) rw = OUTn - 1;
        bSrc[p] = (const float4*)(W + (size_t)rw * MMn + q * 4);
        bDst[p] = Bs2 + r * LDK + q * 4;
    }

    const int qh = lane >> 4;
    const int lr = lane & 15;
    const unsigned short* aRd[2];
    const unsigned short* bRd[4];
#pragma unroll
    for (int i = 0; i < 2; i++) aRd[i] = As2 + (wm * 32 + i * 16 + lr) * LDK + qh * 8;
#pragma unroll
    for (int j = 0; j < 4; j++) bRd[j] = Bs2 + (wn * 64 + j * 16 + lr) * LDK + qh * 8;

    f32x4 acc[2][4];
#pragma unroll
    for (int i = 0; i < 2; i++)
#pragma unroll
        for (int j = 0; j < 4; j++)
            acc[i][j] = (f32x4){0.f, 0.f, 0.f, 0.f};

    for (int k0 = 0; k0 < MMn; k0 += BK) {
        uint4 av = aSrc[k0 >> 3];
        float4 bv[4];
#pragma unroll
        for (int p = 0; p < 4; p++) bv[p] = bSrc[p][k0 >> 2];

        __syncthreads();
        *(uint4*)aDst = av;
#pragma unroll
        for (int p = 0; p < 4; p++) {
            uint2 pk;
            pk.x = (uint32_t)f2bf(bv[p].x) | ((uint32_t)f2bf(bv[p].y) << 16);
            pk.y = (uint32_t)f2bf(bv[p].z) | ((uint32_t)f2bf(bv[p].w) << 16);
            *(uint2*)bDst[p] = pk;
        }
        __syncthreads();

        bf16x8 af[2], bfr[4];
#pragma unroll
        for (int i = 0; i < 2; i++) af[i] = *(const bf16x8*)aRd[i];
#pragma unroll
        for (int j = 0; j < 4; j++) bfr[j] = *(const bf16x8*)bRd[j];
#pragma unroll
        for (int i = 0; i < 2; i++)
#pragma unroll
            for (int j = 0; j < 4; j++)
                acc[i][j] = __builtin_amdgcn_mfma_f32_16x16x32_bf16(
                    af[i], bfr[j], acc[i][j], 0, 0, 0);
    }

#pragma unroll
    for (int j = 0; j < 4; j++) {
        int n = n0 + wn * 64 + j * 16 + lr;
        if (n < OUTn) {
            float bvb = bias[n];
#pragma unroll
            for (int i = 0; i < 2; i++) {
                int mb = m0 + wm * 32 + i * 16 + qh * 4;
#pragma unroll
                for (int reg = 0; reg < 4; reg++) {
                    float v = acc[i][j][reg] + bvb;
                    out[(size_t)(mb + reg) * OUTn + n] = v > 0.f ? v : 0.f;
                }
            }
        }
    }
}

// ---------------------------------------------------------------------------
// ws layout (full path; NEED identical to R4's proven 179,227,648):
//   [0, 32768000)              zb   bf16 [1024][16000]
//   [32768000, 32864000)       tw   float2 [11981] (+pad to 32896000)
//   [32896000, 128896000)      Wbf  bf16 [3000][16000]
//   [128896000, 179227648)     part f32 [4][1024][3072]  (c0 spill aliases
//                              the first 32.77 MB — disjoint lifetimes)
// ---------------------------------------------------------------------------
extern "C" void kernel_launch(void* const* d_in, const int* in_sizes, int n_in,
                              void* d_out, int out_size, void* d_ws, size_t ws_size,
                              hipStream_t stream) {
    const float* x0 = (const float*)d_in[0];
    const float* x1 = (const float*)d_in[1];
    const int*   h0 = (const int*)d_in[2];
    const int*   h1 = (const int*)d_in[3];
    const int*   s0 = (const int*)d_in[4];
    const int*   s1 = (const int*)d_in[5];
    const float* W  = (const float*)d_in[6];
    const float* bb = (const float*)d_in[7];
    float* out = (float*)d_out;

    unsigned char* ws = (unsigned char*)d_ws;
    unsigned short* zb  = (unsigned short*)(ws);
    float2*         tw  = (float2*)(ws + 32768000);
    unsigned short* wbf = (unsigned short*)(ws + 32896000);
    float*          prt = (float*)(ws + 128896000);
    const size_t NEED = 128896000 + 4 * PSTRIDE * sizeof(float);
    const int doW = (ws_size >= NEED) ? 1 : 0;
    // c0 spill: aliases part region (full path) or wbf region (fallback path)
    uint32_t* c0g = doW ? (uint32_t*)(ws + 128896000) : (uint32_t*)(ws + 32896000);

    tw_init_kernel<<<(TWN + 255) / 256, 256, 0, stream>>>(tw);
    fft_conv_kernel<<<Bsz, FBLK, 0, stream>>>(x0, x1, h0, h1, s0, s1, tw,
                                              W, wbf, doW, c0g, zb);

    if (doW) {
        dim3 g((OUTn + 127) / 128, Bsz / 128, 4);
        gemm_sk_kernel<<<g, 256, 0, stream>>>(zb, wbf, prt);
        reduce_kernel<<<Bsz * (OUTn / 4) / 256, 256, 0, stream>>>(prt, bb, out);
    } else {
        dim3 g((OUTn + BN - 1) / BN, Bsz / BM);
        gemm_kernel<<<g, 256, 0, stream>>>(zb, W, bb, out);
    }
}

// Round 2
// 479.396 us; speedup vs baseline: 1.0786x; 1.0354x over previous
//
#include <hip/hip_runtime.h>
#include <stdint.h>

// Problem constants (MCB_42949672960828)
#define Bsz  1024
#define D0n  2048
#define D1n  2048
#define MMn  16000
#define N2   8000    // half-length complex FFT size
#define OUTn 3000
#define HBLK 512     // half-block (one FFT pipeline)
#define TBLK 1024    // threads per fft block (two FFT pipelines)

// Padded LDS layout: X index i -> i + i/20  (one float2 pad per 20)
// Two arrays of 8400 float2 = 134.4 KB <= 160 KB -> 1 block/CU, 16 waves.
#define XSZ  8400

typedef __attribute__((ext_vector_type(8))) short bf16x8;
typedef __attribute__((ext_vector_type(4))) float f32x4;

__device__ __forceinline__ unsigned short f2bf(float f) {
    union { float fv; uint32_t u; } v; v.fv = f;
    return (unsigned short)((v.u + 0x7fffu + ((v.u >> 16) & 1u)) >> 16);
}
__device__ __forceinline__ uint32_t packbf(float2 v) {
    return (uint32_t)f2bf(v.x) | ((uint32_t)f2bf(v.y) << 16);
}

__device__ __forceinline__ float2 operator+(float2 a, float2 b){ return make_float2(a.x+b.x, a.y+b.y); }
__device__ __forceinline__ float2 operator-(float2 a, float2 b){ return make_float2(a.x-b.x, a.y-b.y); }
__device__ __forceinline__ float2 operator*(float s, float2 a){ return make_float2(s*a.x, s*a.y); }
__device__ __forceinline__ float2 cmul(float2 a, float2 b){ return make_float2(a.x*b.x - a.y*b.y, a.x*b.y + a.y*b.x); }

// async 16B global -> LDS (direct-to-shared DMA)
__device__ __forceinline__ void gll16(const void* g, void* l) {
    __builtin_amdgcn_global_load_lds(
        (const __attribute__((address_space(1))) uint32_t*)g,
        (__attribute__((address_space(3))) uint32_t*)l, 16, 0, 0);
}

// ---------------------------------------------------------------------------
// Twiddle table, N2 = 8000, radices [20,20,20].
// stage1 (NC=8000,M=400): tw[p*19+(u-1)] p<400       -> [0,7600)
// stage2 (NC=400, M=20):  tw[7600+p*19+(u-1)] p<20   -> [7600,7980)
// untangle: utw[k] = e^{-2pi i k/8000}, k<=4000      -> [7980,11981)
// ---------------------------------------------------------------------------
#define TWN 11981

__global__ __launch_bounds__(256) void tw_init_kernel(float2* __restrict__ tw) {
    int g = blockIdx.x * 256 + threadIdx.x;
    if (g >= TWN) return;
    float ang;
    if (g < 7600)      { int p = g / 19, u = g % 19 + 1;
                         ang = -6.28318530718f * (float)((p * u) % 8000) / 8000.f; }
    else if (g < 7980) { int e = g - 7600; int p = e / 19, u = e % 19 + 1;
                         ang = -6.28318530718f * (float)((p * u) % 400) / 400.f; }
    else               { int k = g - 7980;
                         ang = -6.28318530718f * (float)k / 8000.f; }
    float s, c; __sincosf(ang, &s, &c);
    tw[g] = make_float2(c, s);
}

// radix-R DFT butterfly; sgn = -1 forward, +1 inverse
template<int R>
__device__ __forceinline__ void dft_r(const float2* a, float2* A, float sgn) {
    if constexpr (R == 4) {
        float2 t0 = a[0] + a[2], t1 = a[0] - a[2];
        float2 t2 = a[1] + a[3], t3 = a[1] - a[3];
        float2 it3 = make_float2(-sgn * t3.y, sgn * t3.x);
        A[0] = t0 + t2;  A[2] = t0 - t2;
        A[1] = t1 + it3; A[3] = t1 - it3;
    } else if constexpr (R == 5) {
        const float c1 = 0.30901699f,  s1 = 0.95105652f;
        const float c2 = -0.80901699f, s2 = 0.58778525f;
        float2 t1 = a[1] + a[4], t3 = a[1] - a[4];
        float2 t2 = a[2] + a[3], t4 = a[2] - a[3];
        float2 b1 = a[0] + c1 * t1 + c2 * t2;
        float2 b2 = a[0] + c2 * t1 + c1 * t2;
        float2 u  = s1 * t3 + s2 * t4;
        float2 v  = s2 * t3 - s1 * t4;
        float2 iu = make_float2(-sgn * u.y, sgn * u.x);
        float2 iv = make_float2(-sgn * v.y, sgn * v.x);
        A[0] = a[0] + t1 + t2;
        A[1] = b1 + iu;  A[4] = b1 - iu;
        A[2] = b2 + iv;  A[3] = b2 - iv;
    } else {  // R == 20: n = n0 + 4*n1 (n0<4,n1<5), k = k1 + 5*k0 (k1<5,k0<4)
        float2 b[4][5];
#pragma unroll
        for (int n0 = 0; n0 < 4; n0++) {
            float2 t[5] = { a[n0], a[n0+4], a[n0+8], a[n0+12], a[n0+16] };
            dft_r<5>(t, b[n0], sgn);
        }
        const float E1c=0.95105652f,  E1s=0.30901699f;
        const float E2c=0.80901699f,  E2s=0.58778525f;
        const float E3c=0.58778525f,  E3s=0.80901699f;
        const float E4c=0.30901699f,  E4s=0.95105652f;
        const float E6c=-0.30901699f, E6s=0.95105652f;
        const float E8c=-0.80901699f, E8s=0.58778525f;
        const float E9c=-0.95105652f, E9s=0.30901699f;
        const float E12c=-0.80901699f,E12s=-0.58778525f;
        b[1][1] = cmul(b[1][1], make_float2(E1c,  sgn*E1s));
        b[1][2] = cmul(b[1][2], make_float2(E2c,  sgn*E2s));
        b[1][3] = cmul(b[1][3], make_float2(E3c,  sgn*E3s));
        b[1][4] = cmul(b[1][4], make_float2(E4c,  sgn*E4s));
        b[2][1] = cmul(b[2][1], make_float2(E2c,  sgn*E2s));
        b[2][2] = cmul(b[2][2], make_float2(E4c,  sgn*E4s));
        b[2][3] = cmul(b[2][3], make_float2(E6c,  sgn*E6s));
        b[2][4] = cmul(b[2][4], make_float2(E8c,  sgn*E8s));
        b[3][1] = cmul(b[3][1], make_float2(E3c,  sgn*E3s));
        b[3][2] = cmul(b[3][2], make_float2(E6c,  sgn*E6s));
        b[3][3] = cmul(b[3][3], make_float2(E9c,  sgn*E9s));
        b[3][4] = cmul(b[3][4], make_float2(E12c, sgn*E12s));
#pragma unroll
        for (int k1 = 0; k1 < 5; k1++) {
            float2 t[4] = { b[0][k1], b[1][k1], b[2][k1], b[3][k1] };
            float2 o[4];
            dft_r<4>(t, o, sgn);
            A[k1] = o[0]; A[k1+5] = o[1]; A[k1+10] = o[2]; A[k1+15] = o[3];
        }
    }
}

// In-place stage over padded X; twiddles from table (inverse = conj).
// Padded index math (pad = idx/20, exact because NC multiples of 20):
//   M=400: idx = p + 400t      -> xi = (p + p/20) + 420t
//   M=20:  idx = 400blk+p+20t  -> xi = 420blk + p + 21t
//   M=1:   idx = 20e + t       -> xi = 21e + t
// start/step select which threads participate (half-block fwd, full-block inv).
template<int NC, int R, bool INV>
__device__ __forceinline__ void fft_stage(float2* X, const float2* __restrict__ tw,
                                          int start, int step) {
    constexpr int M = NC / R;
    constexpr int NBF = N2 / R;    // 400
    constexpr float sgn = INV ? 1.0f : -1.0f;
    for (int e = start; e < NBF; e += step) {
        const int blk = e / M;
        const int p   = e - blk * M;
        int xbase, xstride;
        if constexpr (M == 400)     { xbase = p + p / 20;      xstride = 420; }
        else if constexpr (M == 20) { xbase = blk * 420 + p;   xstride = 21; }
        else                        { xbase = 21 * e;          xstride = 1; }
        float2 a[R];
#pragma unroll
        for (int t = 0; t < R; t++) a[t] = X[xbase + xstride * t];
        if constexpr (INV && M > 1) {
#pragma unroll
            for (int u = 1; u < R; u++) {
                float2 w = tw[p * (R - 1) + (u - 1)];
                a[u] = cmul(a[u], make_float2(w.x, -w.y));
            }
        }
        float2 A[R];
        dft_r<R>(a, A, sgn);
        if constexpr (!INV && M > 1) {
#pragma unroll
            for (int u = 1; u < R; u++) {
                float2 w = tw[p * (R - 1) + (u - 1)];
                A[u] = cmul(A[u], w);
            }
        }
#pragma unroll
        for (int t = 0; t < R; t++) X[xbase + xstride * t] = A[t];
    }
}

// Fused inverse last stage (NC=8000, M=400): inverse twiddle + DFT20,
// write output rows straight to global (coalesced: lanes p consecutive).
__device__ __forceinline__ void inv_last_out(const float2* X, const float2* __restrict__ tw,
                                             uint32_t* __restrict__ zrow,
                                             int start, int step) {
    const float invN = 1.0f / (float)N2;
    for (int e = start; e < 400; e += step) {
        const int p = e;
        const int xb = p + p / 20;
        float2 a[20];
#pragma unroll
        for (int t = 0; t < 20; t++) a[t] = X[xb + 420 * t];
#pragma unroll
        for (int u = 1; u < 20; u++) {
            float2 w = tw[p * 19 + (u - 1)];
            a[u] = cmul(a[u], make_float2(w.x, -w.y));
        }
        float2 A[20];
        dft_r<20>(a, A, 1.0f);
#pragma unroll
        for (int t = 0; t < 20; t++)
            zrow[p + 400 * t] = packbf(make_float2(A[t].x * invN, A[t].y * invN));
    }
}

// padded float address for scatter into Xf (float index h in [0,16000))
__device__ __forceinline__ int fpad(int h) {
    int i = h >> 1;
    return 2 * (i + i / 20) + (h & 1);
}

// W conversion plumbing (fused into fft kernel; 6 batches of 2 float4/thread)
#define WU_TOT 12000000            // (OUTn*MMn)/4 float4 units
#define WU_STRIDE (Bsz * TBLK)     // 1048576

__device__ __forceinline__ void w_issue(const float4* __restrict__ wsrc,
                                        float4* wr, int uid, int bi) {
#pragma unroll
    for (int j = 0; j < 2; j++) {
        size_t u = (size_t)uid + (size_t)(bi * 2 + j) * WU_STRIDE;
        if (u < WU_TOT) wr[j] = wsrc[u];
    }
}
__device__ __forceinline__ void w_consume(unsigned short* __restrict__ wbf,
                                          const float4* wr, int uid, int bi) {
#pragma unroll
    for (int j = 0; j < 2; j++) {
        size_t u = (size_t)uid + (size_t)(bi * 2 + j) * WU_STRIDE;
        if (u < WU_TOT) {
            uint2 pk;
            pk.x = (uint32_t)f2bf(wr[j].x) | ((uint32_t)f2bf(wr[j].y) << 16);
            pk.y = (uint32_t)f2bf(wr[j].z) | ((uint32_t)f2bf(wr[j].w) << 16);
            ((uint2*)wbf)[u] = pk;
        }
    }
}

// ---------------------------------------------------------------------------
// Kernel: count-sketch + circular convolution via even/odd packed half-length
// FFTs. BOTH spectra live in LDS (134.4 KB): waves 0-7 run c0's pipeline on
// X0 while waves 8-15 run c1's on X1. No c0 global spill (-64 MB traffic,
// C0 stays f32), barriers per batch 12 -> 8.
// ---------------------------------------------------------------------------
__global__ __launch_bounds__(TBLK, 4) void fft_conv_kernel(
    const float* __restrict__ x0, const float* __restrict__ x1,
    const int* __restrict__ h0, const int* __restrict__ h1,
    const int* __restrict__ s0, const int* __restrict__ s1,
    const float2* __restrict__ tw,
    const float* __restrict__ W, unsigned short* __restrict__ wbf, int doW,
    unsigned short* __restrict__ zb)  // [Bsz, MMn] bf16
{
    __shared__ float2 X0[XSZ];        // 67200 B (padded), c0 spectrum
    __shared__ float2 X1[XSZ];        // 67200 B (padded), c1 spectrum
    const int b = blockIdx.x;
    const int tid = threadIdx.x;
    const int lt = tid & (HBLK - 1);
    const bool hi = tid >= HBLK;      // wave-uniform half select
    float2* Xm = hi ? X1 : X0;
    const int uid = b * TBLK + tid;
    const float4* wsrc = (const float4*)W;
    const float2* utw = tw + 7980;

    float4 wr[2];
    if (doW) w_issue(wsrc, wr, uid, 0);

    // ---- zero both padded arrays ----
    for (int i = tid; i < XSZ; i += TBLK) {
        X0[i] = make_float2(0.f, 0.f);
        X1[i] = make_float2(0.f, 0.f);
    }
    __syncthreads();

    // ---- scatter c0 (half 0) and c1 (half 1), one float4/int4 per thread ----
    {
        const float* xp = hi ? x1 : x0;
        const int*   hp = hi ? h1 : h0;
        const int*   sp = hi ? s1 : s0;
        float* Xf = (float*)Xm;
        float4 xv = ((const float4*)(xp + (size_t)b * D0n))[lt];
        int4   hv = ((const int4*)hp)[lt];
        int4   sv = ((const int4*)sp)[lt];
        atomicAdd(&Xf[fpad(hv.x)], xv.x * (float)(2 * sv.x - 1));
        atomicAdd(&Xf[fpad(hv.y)], xv.y * (float)(2 * sv.y - 1));
        atomicAdd(&Xf[fpad(hv.z)], xv.z * (float)(2 * sv.z - 1));
        atomicAdd(&Xf[fpad(hv.w)], xv.w * (float)(2 * sv.w - 1));
    }
    __syncthreads();

    // ---- forward FFTs, both halves in lockstep ----
    fft_stage<8000,20,false>(Xm, tw, lt, HBLK);        __syncthreads();
    if (doW) { w_consume(wbf, wr, uid, 0); w_issue(wsrc, wr, uid, 1); }
    fft_stage<400, 20,false>(Xm, tw + 7600, lt, HBLK); __syncthreads();
    if (doW) { w_consume(wbf, wr, uid, 1); w_issue(wsrc, wr, uid, 2); }
    fft_stage<20,  20,false>(Xm, tw, lt, HBLK);        __syncthreads();
    if (doW) { w_consume(wbf, wr, uid, 2); w_issue(wsrc, wr, uid, 3); }

    // ---- untangle + multiply + retangle (pairs k, 8000-k); D -> X0 ----
    for (int t = tid; t <= 4000; t += TBLK) {
        int k;
        if (t == 4000) k = 4000;
        else { int d2 = t % 10, r = t / 10; k = (r / 20) + 20 * (r % 20) + 400 * d2; }
        int ka = k % 20, ka2 = (k / 20) % 20;
        int pa  = ka * 400 + ka2 * 20 + (k / 400);
        int xpa = pa + ka * 20 + ka2;                 // pa + pa/20
        int kk = (k == 0) ? 0 : (N2 - k);
        int ma = kk % 20, ma2 = (kk / 20) % 20;
        int pb  = ma * 400 + ma2 * 20 + (kk / 400);
        int xpb = pb + ma * 20 + ma2;                 // pb + pb/20
        float2 C0a = X0[xpa], C0b = X0[xpb];
        float2 C1a = X1[xpa], C1b = X1[xpb];
        float2 E0 = make_float2(0.5f * (C0a.x + C0b.x), 0.5f * (C0a.y - C0b.y));
        float2 dv0 = make_float2(C0a.x - C0b.x, C0a.y + C0b.y);
        float2 O0 = make_float2(0.5f * dv0.y, -0.5f * dv0.x);
        float2 E1 = make_float2(0.5f * (C1a.x + C1b.x), 0.5f * (C1a.y - C1b.y));
        float2 dv1 = make_float2(C1a.x - C1b.x, C1a.y + C1b.y);
        float2 O1 = make_float2(0.5f * dv1.y, -0.5f * dv1.x);
        float2 Wq = utw[k];
        float2 Ez = cmul(E0, E1) + cmul(Wq, cmul(O0, O1));
        float2 Oz = cmul(E0, O1) + cmul(O0, E1);
        X0[xpa] = make_float2(Ez.x - Oz.y, Ez.y + Oz.x);       // D[k]
        X0[xpb] = make_float2(Ez.x + Oz.y, Oz.x - Ez.y);       // D[8000-k]
    }
    __syncthreads();
    if (doW) { w_consume(wbf, wr, uid, 3); w_issue(wsrc, wr, uid, 4); }

    // ---- inverse FFT on X0 (400 butterflies/stage over the full block) ----
    fft_stage<20,  20,true>(X0, tw, tid, TBLK);        __syncthreads();
    if (doW) { w_consume(wbf, wr, uid, 4); w_issue(wsrc, wr, uid, 5); }
    fft_stage<400, 20,true>(X0, tw + 7600, tid, TBLK); __syncthreads();
    if (doW) w_consume(wbf, wr, uid, 5);
    uint32_t* zrow = (uint32_t*)(zb + (size_t)b * MMn);
    inv_last_out(X0, tw, zrow, tid, TBLK);  // last stage + scale + output fused
}

// ---------------------------------------------------------------------------
// Split-K GEMM: partial[s] = Z[:, ks:ke] @ Wb[:, ks:ke]^T  (validated R3/R4)
// ---------------------------------------------------------------------------
#define PCOLS 3072
#define PSTRIDE ((size_t)Bsz * PCOLS)

__global__ __launch_bounds__(256, 3) void gemm_sk_kernel(
    const unsigned short* __restrict__ Z,    // [1024,16000] bf16
    const unsigned short* __restrict__ Wb,   // [3000,16000] bf16
    float* __restrict__ part)                // [4][1024][3072] f32
{
    __shared__ __align__(16) unsigned char As[16384];
    __shared__ __align__(16) unsigned char Bs[16384];

    const int tid = threadIdx.x;
    const int n0 = blockIdx.x * 128;
    const int m0 = blockIdx.y * 128;
    const int sp = blockIdx.z;
    const int lane = tid & 63;
    const int w = tid >> 6, wm = w >> 1, wn = w & 1;
    const int lr = lane & 15, qh = lane >> 4;

    const unsigned char* aSrc[4]; const unsigned char* bSrc[4];
    int aLds[4], bLds[4];
#pragma unroll
    for (int i = 0; i < 4; i++) {
        int slot = i * 256 + tid;
        int r = slot >> 3, qp = slot & 7;
        int q = qp ^ (r & 7);
        aSrc[i] = (const unsigned char*)(Z + (size_t)(m0 + r) * MMn + q * 8);
        aLds[i] = slot * 16;
        int rw = n0 + r; if (rw > OUTn - 1) rw = OUTn - 1;
        bSrc[i] = (const unsigned char*)(Wb + (size_t)rw * MMn + q * 8);
        bLds[i] = slot * 16;
    }

    int aOff[4], bOff[4];
#pragma unroll
    for (int i = 0; i < 4; i++) {
        aOff[i] = (wm * 64 + i * 16 + lr) * 128 + ((qh ^ (lr & 7)) * 16);
        bOff[i] = (wn * 64 + i * 16 + lr) * 128 + ((qh ^ (lr & 7)) * 16);
    }

    f32x4 acc[4][4];
#pragma unroll
    for (int i = 0; i < 4; i++)
#pragma unroll
        for (int j = 0; j < 4; j++)
            acc[i][j] = (f32x4){0.f, 0.f, 0.f, 0.f};

    const int it_b = (250 * sp) / 4, it_e = (250 * (sp + 1)) / 4;
    for (int it = it_b; it < it_e; ++it) {
        const size_t koff = (size_t)it * 128;
        __syncthreads();
#pragma unroll
        for (int i = 0; i < 4; i++) {
            gll16(aSrc[i] + koff, As + aLds[i]);
            gll16(bSrc[i] + koff, Bs + bLds[i]);
        }
        __syncthreads();
#pragma unroll
        for (int kk = 0; kk < 2; kk++) {
            const int kx = kk << 6;
            bf16x8 af[4], bfv[4];
#pragma unroll
            for (int i = 0; i < 4; i++) af[i]  = *(const bf16x8*)(As + (aOff[i] ^ kx));
#pragma unroll
            for (int j = 0; j < 4; j++) bfv[j] = *(const bf16x8*)(Bs + (bOff[j] ^ kx));
#pragma unroll
            for (int i = 0; i < 4; i++)
#pragma unroll
                for (int j = 0; j < 4; j++)
                    acc[i][j] = __builtin_amdgcn_mfma_f32_16x16x32_bf16(
                        af[i], bfv[j], acc[i][j], 0, 0, 0);
        }
    }

    float* pdst = part + (size_t)sp * PSTRIDE;
#pragma unroll
    for (int j = 0; j < 4; j++) {
        int n = n0 + wn * 64 + j * 16 + lr;
#pragma unroll
        for (int i = 0; i < 4; i++) {
            int mb = m0 + wm * 64 + i * 16 + qh * 4;
#pragma unroll
            for (int reg = 0; reg < 4; reg++)
                pdst[(size_t)(mb + reg) * PCOLS + n] = acc[i][j][reg];
        }
    }
}

// out = relu(sum_s part[s] + bias)
__global__ __launch_bounds__(256) void reduce_kernel(
    const float* __restrict__ part, const float* __restrict__ bias,
    float* __restrict__ out)
{
    int idx = blockIdx.x * 256 + threadIdx.x;
    int b = idx / 750, oq = idx - b * 750;
    int o = oq * 4;
    const float* p = part + (size_t)b * PCOLS + o;
    float4 s0 = *(const float4*)(p);
    float4 s1 = *(const float4*)(p + PSTRIDE);
    float4 s2 = *(const float4*)(p + 2 * PSTRIDE);
    float4 s3 = *(const float4*)(p + 3 * PSTRIDE);
    float4 bv = *(const float4*)(bias + o);
    float4 r;
    r.x = s0.x + s1.x + s2.x + s3.x + bv.x; r.x = r.x > 0.f ? r.x : 0.f;
    r.y = s0.y + s1.y + s2.y + s3.y + bv.y; r.y = r.y > 0.f ? r.y : 0.f;
    r.z = s0.z + s1.z + s2.z + s3.z + bv.z; r.z = r.z > 0.f ? r.z : 0.f;
    r.w = s0.w + s1.w + s2.w + s3.w + bv.w; r.w = r.w > 0.f ? r.w : 0.f;
    *(float4*)(out + (size_t)b * OUTn + o) = r;
}

// ---------------------------------------------------------------------------
// Fallback GEMM (R2, validated): direct out, W f32 converted in-loop.
// ---------------------------------------------------------------------------
#define BM 64
#define BN 128
#define BK 32
#define LDK 40

__global__ __launch_bounds__(256) void gemm_kernel(
    const unsigned short* __restrict__ Z, const float* __restrict__ W,
    const float* __restrict__ bias, float* __restrict__ out)
{
    __shared__ __align__(16) unsigned short As2[BM * LDK];
    __shared__ __align__(16) unsigned short Bs2[BN * LDK];

    const int tid = threadIdx.x;
    const int m0 = blockIdx.y * BM;
    const int n0 = blockIdx.x * BN;
    const int lane = tid & 63;
    const int w  = tid >> 6;
    const int wm = w >> 1;
    const int wn = w & 1;

    const int ar = tid >> 2, aq = tid & 3;
    const uint4* aSrc = (const uint4*)(Z + (size_t)(m0 + ar) * MMn + aq * 8);
    unsigned short* aDst = As2 + ar * LDK + aq * 8;

    const float4* bSrc[4];
    unsigned short* bDst[4];
#pragma unroll
    for (int p = 0; p < 4; p++) {
        int ch = tid + 256 * p;
        int r = ch >> 3, q = ch & 7;
        int rw = n0 + r; if (rw > OUTn - 1) rw = OUTn - 1;
        bSrc[p] = (const float4*)(W + (size_t)rw * MMn + q * 4);
        bDst[p] = Bs2 + r * LDK + q * 4;
    }

    const int qh = lane >> 4;
    const int lr = lane & 15;
    const unsigned short* aRd[2];
    const unsigned short* bRd[4];
#pragma unroll
    for (int i = 0; i < 2; i++) aRd[i] = As2 + (wm * 32 + i * 16 + lr) * LDK + qh * 8;
#pragma unroll
    for (int j = 0; j < 4; j++) bRd[j] = Bs2 + (wn * 64 + j * 16 + lr) * LDK + qh * 8;

    f32x4 acc[2][4];
#pragma unroll
    for (int i = 0; i < 2; i++)
#pragma unroll
        for (int j = 0; j < 4; j++)
            acc[i][j] = (f32x4){0.f, 0.f, 0.f, 0.f};

    for (int k0 = 0; k0 < MMn; k0 += BK) {
        uint4 av = aSrc[k0 >> 3];
        float4 bv[4];
#pragma unroll
        for (int p = 0; p < 4; p++) bv[p] = bSrc[p][k0 >> 2];

        __syncthreads();
        *(uint4*)aDst = av;
#pragma unroll
        for (int p = 0; p < 4; p++) {
            uint2 pk;
            pk.x = (uint32_t)f2bf(bv[p].x) | ((uint32_t)f2bf(bv[p].y) << 16);
            pk.y = (uint32_t)f2bf(bv[p].z) | ((uint32_t)f2bf(bv[p].w) << 16);
            *(uint2*)bDst[p] = pk;
        }
        __syncthreads();

        bf16x8 af[2], bfr[4];
#pragma unroll
        for (int i = 0; i < 2; i++) af[i] = *(const bf16x8*)aRd[i];
#pragma unroll
        for (int j = 0; j < 4; j++) bfr[j] = *(const bf16x8*)bRd[j];
#pragma unroll
        for (int i = 0; i < 2; i++)
#pragma unroll
            for (int j = 0; j < 4; j++)
                acc[i][j] = __builtin_amdgcn_mfma_f32_16x16x32_bf16(
                    af[i], bfr[j], acc[i][j], 0, 0, 0);
    }

#pragma unroll
    for (int j = 0; j < 4; j++) {
        int n = n0 + wn * 64 + j * 16 + lr;
        if (n < OUTn) {
            float bvb = bias[n];
#pragma unroll
            for (int i = 0; i < 2; i++) {
                int mb = m0 + wm * 32 + i * 16 + qh * 4;
#pragma unroll
                for (int reg = 0; reg < 4; reg++) {
                    float v = acc[i][j][reg] + bvb;
                    out[(size_t)(mb + reg) * OUTn + n] = v > 0.f ? v : 0.f;
                }
            }
        }
    }
}

// ---------------------------------------------------------------------------
// ws layout (full path; NEED identical to R4's proven 179,227,648):
//   [0, 32768000)              zb   bf16 [1024][16000]
//   [32768000, 32864000)       tw   float2 [11981] (+pad to 32896000)
//   [32896000, 128896000)      Wbf  bf16 [3000][16000]
//   [128896000, 179227648)     part f32 [4][1024][3072]
//   (c0 spill eliminated this round — both spectra stay in LDS)
// ---------------------------------------------------------------------------
extern "C" void kernel_launch(void* const* d_in, const int* in_sizes, int n_in,
                              void* d_out, int out_size, void* d_ws, size_t ws_size,
                              hipStream_t stream) {
    const float* x0 = (const float*)d_in[0];
    const float* x1 = (const float*)d_in[1];
    const int*   h0 = (const int*)d_in[2];
    const int*   h1 = (const int*)d_in[3];
    const int*   s0 = (const int*)d_in[4];
    const int*   s1 = (const int*)d_in[5];
    const float* W  = (const float*)d_in[6];
    const float* bb = (const float*)d_in[7];
    float* out = (float*)d_out;

    unsigned char* ws = (unsigned char*)d_ws;
    unsigned short* zb  = (unsigned short*)(ws);
    float2*         tw  = (float2*)(ws + 32768000);
    unsigned short* wbf = (unsigned short*)(ws + 32896000);
    float*          prt = (float*)(ws + 128896000);
    const size_t NEED = 128896000 + 4 * PSTRIDE * sizeof(float);
    const int doW = (ws_size >= NEED) ? 1 : 0;

    tw_init_kernel<<<(TWN + 255) / 256, 256, 0, stream>>>(tw);
    fft_conv_kernel<<<Bsz, TBLK, 0, stream>>>(x0, x1, h0, h1, s0, s1, tw,
                                              W, wbf, doW, zb);

    if (doW) {
        dim3 g((OUTn + 127) / 128, Bsz / 128, 4);
        gemm_sk_kernel<<<g, 256, 0, stream>>>(zb, wbf, prt);
        reduce_kernel<<<Bsz * (OUTn / 4) / 256, 256, 0, stream>>>(prt, bb, out);
    } else {
        dim3 g((OUTn + BN - 1) / BN, Bsz / BM);
        gemm_kernel<<<g, 256, 0, stream>>>(zb, W, bb, out);
    }
}